// Round 1
// baseline (1941.616 us; speedup 1.0000x reference)
//
#include <hip/hip_runtime.h>
#include <hip/hip_bf16.h>
#include <stdint.h>

// Problem: y[M,N] = x[M,K] @ (qW[N,K]/w_scale)^T + q_bias[N]/b_scale
#define M_DIM 8192
#define N_DIM 16384
#define K_DIM 4096
#define BM 128
#define BN 128
#define BK 32

typedef __attribute__((ext_vector_type(8))) short short8;      // 8 bf16 (4 VGPRs)
typedef __attribute__((ext_vector_type(4))) float floatx4;     // MFMA acc
typedef __attribute__((ext_vector_type(4))) unsigned int uint4v;

__device__ __forceinline__ unsigned short f2bf(float f) {
    // round-to-nearest-even fp32 -> bf16
    unsigned int u = __float_as_uint(f);
    u += 0x7fffu + ((u >> 16) & 1u);
    return (unsigned short)(u >> 16);
}

// ---------------- fp32 -> bf16 conversion (memory-bound) ----------------
__global__ void __launch_bounds__(256) cvt_f32_bf16(const float* __restrict__ src,
                                                    unsigned short* __restrict__ dst,
                                                    long long n) {
    long long i = ((long long)blockIdx.x * 256 + threadIdx.x) * 8;
    if (i >= n) return;
    float4 a = *(const float4*)(src + i);
    float4 b = *(const float4*)(src + i + 4);
    union { unsigned short us[8]; uint4v v; } o;
    o.us[0] = f2bf(a.x); o.us[1] = f2bf(a.y); o.us[2] = f2bf(a.z); o.us[3] = f2bf(a.w);
    o.us[4] = f2bf(b.x); o.us[5] = f2bf(b.y); o.us[6] = f2bf(b.z); o.us[7] = f2bf(b.w);
    *(uint4v*)(dst + i) = o.v;
}

__device__ __forceinline__ void gld_lds16(const unsigned short* g, unsigned short* l) {
    __builtin_amdgcn_global_load_lds((const __attribute__((address_space(1))) void*)g,
                                     (__attribute__((address_space(3))) void*)l, 16, 0, 0);
}

// ---------------- bf16 GEMM, B^T layout (m97 structure) ----------------
// A [M,K] bf16, Bt [N,K] bf16 (both K-contiguous). C[M,N] fp32.
__global__ void __launch_bounds__(256) gemm_bt_bf16(
    const unsigned short* __restrict__ A,
    const unsigned short* __restrict__ Bt,
    const float* __restrict__ qbias,
    const float* __restrict__ wscale,
    const float* __restrict__ bscale,
    float* __restrict__ C)
{
    __shared__ __align__(16) unsigned short As[BM * BK];  // 8 KB
    __shared__ __align__(16) unsigned short Bs[BN * BK];  // 8 KB

    const int t    = threadIdx.x;
    const int lane = t & 63;
    const int wave = t >> 6;
    const int wm   = (wave >> 1) * 64;   // wave's M offset in tile
    const int wn   = (wave & 1) * 64;    // wave's N offset in tile
    const int bm   = blockIdx.y * BM;
    const int bn   = blockIdx.x * BN;

    floatx4 acc[4][4];
#pragma unroll
    for (int i = 0; i < 4; i++)
#pragma unroll
        for (int j = 0; j < 4; j++) acc[i][j] = floatx4{0.f, 0.f, 0.f, 0.f};

    // staging: thread t loads 16 B at tile-flat byte offset t*16 (rows 0..63),
    // and a second 16 B at 4096 + t*16 (rows 64..127). Matches the HW
    // wave-uniform-base + lane*16 LDS scatter of global_load_lds.
    const int srow = t >> 2;           // 0..63
    const int scol = (t & 3) * 8;      // 0,8,16,24 (bf16 elems)
    const unsigned short* ag0 = A  + (size_t)(bm + srow) * K_DIM + scol;
    const unsigned short* ag1 = ag0 + (size_t)64 * K_DIM;
    const unsigned short* bg0 = Bt + (size_t)(bn + srow) * K_DIM + scol;
    const unsigned short* bg1 = bg0 + (size_t)64 * K_DIM;
    unsigned short* la0 = As + t * 8;
    unsigned short* la1 = As + 64 * BK + t * 8;
    unsigned short* lb0 = Bs + t * 8;
    unsigned short* lb1 = Bs + 64 * BK + t * 8;

    const int fr = lane & 15;   // fragment row (A) / col (B)
    const int fq = lane >> 4;   // quad
    const int k0 = fq * 8;      // fragment k offset

    for (int kt = 0; kt < K_DIM; kt += BK) {
        gld_lds16(ag0 + kt, la0);
        gld_lds16(ag1 + kt, la1);
        gld_lds16(bg0 + kt, lb0);
        gld_lds16(bg1 + kt, lb1);
        __syncthreads();   // compiler emits vmcnt(0) drain before barrier

        short8 af[4], bf[4];
#pragma unroll
        for (int mi = 0; mi < 4; mi++)
            af[mi] = *(const short8*)(As + (wm + mi * 16 + fr) * BK + k0);
#pragma unroll
        for (int ni = 0; ni < 4; ni++)
            bf[ni] = *(const short8*)(Bs + (wn + ni * 16 + fr) * BK + k0);

#pragma unroll
        for (int mi = 0; mi < 4; mi++)
#pragma unroll
            for (int ni = 0; ni < 4; ni++)
                acc[mi][ni] = __builtin_amdgcn_mfma_f32_16x16x32_bf16(
                    af[mi], bf[ni], acc[mi][ni], 0, 0, 0);
        __syncthreads();
    }

    // epilogue: y = acc/w_scale + q_bias/b_scale
    const float inv_ws = 1.0f / wscale[0];
    const float inv_bs = 1.0f / bscale[0];
#pragma unroll
    for (int mi = 0; mi < 4; mi++) {
#pragma unroll
        for (int ni = 0; ni < 4; ni++) {
            const int col = bn + wn + ni * 16 + fr;
            const float bias = qbias[col] * inv_bs;
#pragma unroll
            for (int r = 0; r < 4; r++) {
                const int row = bm + wm + mi * 16 + fq * 4 + r;
                C[(size_t)row * N_DIM + col] = acc[mi][ni][r] * inv_ws + bias;
            }
        }
    }
}

// ---------------- fallback: fp32 inputs, inline bf16 convert ----------------
__global__ void __launch_bounds__(256) gemm_bt_f32in(
    const float* __restrict__ A,
    const float* __restrict__ Bt,
    const float* __restrict__ qbias,
    const float* __restrict__ wscale,
    const float* __restrict__ bscale,
    float* __restrict__ C)
{
    __shared__ __align__(16) unsigned short As[BM * BK];
    __shared__ __align__(16) unsigned short Bs[BN * BK];

    const int t    = threadIdx.x;
    const int lane = t & 63;
    const int wave = t >> 6;
    const int wm   = (wave >> 1) * 64;
    const int wn   = (wave & 1) * 64;
    const int bm   = blockIdx.y * BM;
    const int bn   = blockIdx.x * BN;

    floatx4 acc[4][4];
#pragma unroll
    for (int i = 0; i < 4; i++)
#pragma unroll
        for (int j = 0; j < 4; j++) acc[i][j] = floatx4{0.f, 0.f, 0.f, 0.f};

    // staging: thread t covers row t>>1 (0..127), cols (t&1)*16 .. +16
    const int srow  = t >> 1;
    const int scol  = (t & 1) * 16;
    const float* ag = A  + (size_t)(bm + srow) * K_DIM + scol;
    const float* bg = Bt + (size_t)(bn + srow) * K_DIM + scol;
    unsigned short* la = As + srow * BK + scol;
    unsigned short* lb = Bs + srow * BK + scol;

    const int fr = lane & 15;
    const int fq = lane >> 4;
    const int k0 = fq * 8;

    for (int kt = 0; kt < K_DIM; kt += BK) {
        union { unsigned short us[8]; uint4v v; } oa, ob;
#pragma unroll
        for (int h = 0; h < 2; h++) {
            float4 a0 = *(const float4*)(ag + kt + h * 8);
            float4 a1 = *(const float4*)(ag + kt + h * 8 + 4);
            oa.us[0] = f2bf(a0.x); oa.us[1] = f2bf(a0.y); oa.us[2] = f2bf(a0.z); oa.us[3] = f2bf(a0.w);
            oa.us[4] = f2bf(a1.x); oa.us[5] = f2bf(a1.y); oa.us[6] = f2bf(a1.z); oa.us[7] = f2bf(a1.w);
            *(uint4v*)(la + h * 8) = oa.v;
            float4 b0 = *(const float4*)(bg + kt + h * 8);
            float4 b1 = *(const float4*)(bg + kt + h * 8 + 4);
            ob.us[0] = f2bf(b0.x); ob.us[1] = f2bf(b0.y); ob.us[2] = f2bf(b0.z); ob.us[3] = f2bf(b0.w);
            ob.us[4] = f2bf(b1.x); ob.us[5] = f2bf(b1.y); ob.us[6] = f2bf(b1.z); ob.us[7] = f2bf(b1.w);
            *(uint4v*)(lb + h * 8) = ob.v;
        }
        __syncthreads();

        short8 af[4], bfr[4];
#pragma unroll
        for (int mi = 0; mi < 4; mi++)
            af[mi] = *(const short8*)(As + (wm + mi * 16 + fr) * BK + k0);
#pragma unroll
        for (int ni = 0; ni < 4; ni++)
            bfr[ni] = *(const short8*)(Bs + (wn + ni * 16 + fr) * BK + k0);

#pragma unroll
        for (int mi = 0; mi < 4; mi++)
#pragma unroll
            for (int ni = 0; ni < 4; ni++)
                acc[mi][ni] = __builtin_amdgcn_mfma_f32_16x16x32_bf16(
                    af[mi], bfr[ni], acc[mi][ni], 0, 0, 0);
        __syncthreads();
    }

    const float inv_ws = 1.0f / wscale[0];
    const float inv_bs = 1.0f / bscale[0];
#pragma unroll
    for (int mi = 0; mi < 4; mi++) {
#pragma unroll
        for (int ni = 0; ni < 4; ni++) {
            const int col = bn + wn + ni * 16 + fr;
            const float bias = qbias[col] * inv_bs;
#pragma unroll
            for (int r = 0; r < 4; r++) {
                const int row = bm + wm + mi * 16 + fq * 4 + r;
                C[(size_t)row * N_DIM + col] = acc[mi][ni][r] * inv_ws + bias;
            }
        }
    }
}

extern "C" void kernel_launch(void* const* d_in, const int* in_sizes, int n_in,
                              void* d_out, int out_size, void* d_ws, size_t ws_size,
                              hipStream_t stream) {
    const float* x      = (const float*)d_in[0];   // [8192, 4096]
    const float* qw     = (const float*)d_in[1];   // [16384, 4096]
    const float* wscale = (const float*)d_in[2];   // scalar
    const float* qbias  = (const float*)d_in[3];   // [16384]
    const float* bscale = (const float*)d_in[4];   // scalar
    float* out = (float*)d_out;

    const size_t needA = (size_t)M_DIM * K_DIM * sizeof(unsigned short); //  64 MiB
    const size_t needB = (size_t)N_DIM * K_DIM * sizeof(unsigned short); // 128 MiB
    dim3 grid(N_DIM / BN, M_DIM / BM);  // (128, 64)

    if (ws_size >= needA + needB) {
        unsigned short* a_bf = (unsigned short*)d_ws;
        unsigned short* b_bf = (unsigned short*)((char*)d_ws + needA);
        const long long nA = (long long)M_DIM * K_DIM;
        const long long nB = (long long)N_DIM * K_DIM;
        cvt_f32_bf16<<<(int)(nA / 8 / 256), 256, 0, stream>>>(x, a_bf, nA);
        cvt_f32_bf16<<<(int)(nB / 8 / 256), 256, 0, stream>>>(qw, b_bf, nB);
        gemm_bt_bf16<<<grid, 256, 0, stream>>>(a_bf, b_bf, qbias, wscale, bscale, out);
    } else {
        gemm_bt_f32in<<<grid, 256, 0, stream>>>(x, qw, qbias, wscale, bscale, out);
    }
}